// Round 19
// baseline (4019.641 us; speedup 1.0000x reference)
//
#include <hip/hip_runtime.h>
#include <math.h>

// VQ-VAE quantizer: N=16384 pixels, D=256, K=8192 codes.
// d_out (float32): [0]=loss, [1..]=z_q_x, [4194305]=perplexity, [4194306..]=idx.
//
// r19 = r18 (verified MFMA candidate-prune + batched exact eval) with:
//  (a) eh-only approx (el plane dropped; eps<=5.1e-5, TAU=2.5e-4 covers with
//      1.8x margin) -> half the MFMA/B-reads/E-writes/cvt;
//  (b) XOR-swizzled LDS (EB [code][64], Xh [px][256], elem ^ 8*(row&7)) ->
//      bank-balanced reads AND writes (r18: ECROW=72/XROW=264 2-way aliased);
//  (c) A-fragments preloaded to registers (32 VGPR, X loop-invariant) ->
//      zero Xh reads in main loop.
// Exact path unchanged: d=0..255 fp32 FMA chain, lexicographic u64 atomicMin.

typedef _Float16 f16x8 __attribute__((ext_vector_type(8)));
typedef float f32x4 __attribute__((ext_vector_type(4)));

#define K_EMB 8192
#define D_EMB 256
#define NPIX  16384
#define NDTOT 4194304

#define OUT_LOSS 0
#define OUT_ZQ   1
#define OUT_PERP 4194305
#define OUT_IDX  4194306

// ws: [0]sse f32; [256]hist int[8192]; [33024]se2 f32[8192]; [65792]sx2 f32[16384]
#define WS_HIST_OFF 256
#define WS_SE2_OFF  33024
#define WS_SX2_OFF  65792

#define TAU 2.5e-4f   // >= grid 3.05e-5 + 2*eps(5.1e-5) + slack

// geometry: block = 64 px, loops 64 code-tiles of 128; schunk = 128c x 64d.
#define TN 64
#define NSTEP 256              // 64 nt x 4 dchunks
#define EBUF 8192              // fp16 per buffer: 128 codes x 64 d
#define QCAP 2048

// LDS layout (bytes)
#define LDS_EB    0                       // 2 x EBUF fp16 = 32768
#define LDS_XH    32768                   // 64 x 256 fp16 = 32768
#define LDS_PXMIN 65536                   // 64 x u64 = 512
#define LDS_QCNT  66048                   // int
#define LDS_QUEUE 66064                   // QCAP x u32 = 8192
#define SMEM_BYTES 74256

// ---------------------------------------------------------------------------
__global__ void sx2_kernel(const float* __restrict__ z,
                           float* __restrict__ sx2) {
#pragma clang fp contract(off)
    int n = blockIdx.x * 256 + threadIdx.x;
    int b = n >> 10, hw = n & 1023;
    const float* zb = z + (size_t)b * (D_EMB * 1024) + hw;
    float half[2];
#pragma unroll
    for (int h = 0; h < 2; ++h) {
        float r[8];
#pragma unroll
        for (int j = 0; j < 8; ++j) {
            float v = zb[(size_t)(h * 128 + j) * 1024];
            r[j] = v * v;
        }
        for (int i = 8; i < 128; i += 8)
#pragma unroll
            for (int j = 0; j < 8; ++j) {
                float v = zb[(size_t)(h * 128 + i + j) * 1024];
                float sq = v * v;
                r[j] = r[j] + sq;
            }
        half[h] = ((r[0] + r[1]) + (r[2] + r[3]))
                + ((r[4] + r[5]) + (r[6] + r[7]));
    }
    sx2[n] = half[0] + half[1];
}

// ---------------------------------------------------------------------------
__global__ void se2_kernel(const float* __restrict__ emb,
                           float* __restrict__ se2) {
#pragma clang fp contract(off)
    int k = blockIdx.x * 256 + threadIdx.x;
    const float* e = emb + (size_t)k * D_EMB;
    float half[2];
#pragma unroll
    for (int h = 0; h < 2; ++h) {
        float r[8];
#pragma unroll
        for (int j = 0; j < 8; ++j) {
            float v = e[h * 128 + j];
            r[j] = v * v;
        }
        for (int i = 8; i < 128; i += 8)
#pragma unroll
            for (int j = 0; j < 8; ++j) {
                float v = e[h * 128 + i + j];
                float sq = v * v;
                r[j] = r[j] + sq;
            }
        half[h] = ((r[0] + r[1]) + (r[2] + r[3]))
                + ((r[4] + r[5]) + (r[6] + r[7]));
    }
    se2[k] = half[0] + half[1];
}

// ---------------------------------------------------------------------------
static __device__ __forceinline__ float f4c(float4 q, int j) {
    return (j == 0) ? q.x : (j == 1) ? q.y : (j == 2) ? q.z : q.w;
}

// exact np-semantics distance (verified r3-r18)
static __device__ __forceinline__ float exact_g(
        const float* __restrict__ z, const float* __restrict__ emb,
        const float* __restrict__ se2, const float* __restrict__ sx2,
        int n, int k) {
#pragma clang fp contract(off)
    const float* xp = z + (size_t)(n >> 10) * 262144 + (n & 1023);
    const float* ep = emb + (size_t)k * 256;
    float s = 0.0f;
    for (int d = 0; d < 256; ++d)
        s = __builtin_fmaf(xp[(size_t)d * 1024], ep[d], s);
    float A = sx2[n] + se2[k];
    return A - 2.0f * s;
}

// ---------------------------------------------------------------------------
// MFMA prune kernel. Grid 256 (one 64-px tile), 512 thr = 8 waves
// (wr 0..3: 16-px tiles, wc 0..1: 64-code halves). Loops 64 code-tiles.
// mfma_f32_16x16x32_f16; A-frag lane: A[l&15][8*(l>>4)+j]; B-frag:
// B[8*(l>>4)+j][l&15]; D: row=(l>>4)*4+j, col=l&15 (r17/r18-verified).
__global__ __launch_bounds__(512, 1) void mfma_kernel(
        const float* __restrict__ z, const float* __restrict__ emb,
        const float* __restrict__ sx2, const float* __restrict__ se2,
        float* __restrict__ out_idx, int* __restrict__ hist) {
#pragma clang fp contract(off)
    extern __shared__ char sm[];
    _Float16* EB   = (_Float16*)(sm + LDS_EB);     // [2][128][64] swizzled
    _Float16* Xh   = (_Float16*)(sm + LDS_XH);     // [64][256] swizzled
    unsigned long long* pxmin = (unsigned long long*)(sm + LDS_PXMIN);
    int*      qcnt  = (int*)(sm + LDS_QCNT);
    unsigned* queue = (unsigned*)(sm + LDS_QUEUE);

    const int t    = threadIdx.x;
    const int lane = t & 63;
    const int w    = t >> 6;
    const int wr   = w >> 1, wc = w & 1;
    const int lc   = lane & 15;
    const int lg   = lane >> 4;
    const int n0   = blockIdx.x * TN;
    const int b    = n0 >> 10, hw0 = n0 & 1023;
    const float* zb = z + (size_t)b * 262144 + hw0;

    if (t < 64) pxmin[t] = ~0ull;
    if (t == 0) *qcnt = 0;

    // ---- stage X once: [d][px] f32 -> transpose+cvt -> Xh swizzled ----
    {
        float* Xtmp = (float*)(sm + LDS_EB);       // 64d x 68px f32 slab
#pragma unroll
        for (int slab = 0; slab < 4; ++slab) {
            {
                int px = t & 63, dr = t >> 6;
#pragma unroll
                for (int r = 0; r < 8; ++r) {
                    int dl = dr * 8 + r;
                    Xtmp[dl * 68 + px] = zb[(size_t)(slab * 64 + dl) * 1024 + px];
                }
            }
            __syncthreads();
            {
                int px = t & 63, g = t >> 6;
                f16x8 v;
#pragma unroll
                for (int i = 0; i < 8; ++i)
                    v[i] = (_Float16)Xtmp[(g * 8 + i) * 68 + px];
                int off = (slab * 64 + g * 8) ^ (8 * (px & 7));
                *(f16x8*)&Xh[px * 256 + off] = v;
            }
            __syncthreads();
        }
    }

    // E staging map: thread -> code = t>>2 (0..127), sq = t&3 (16-d chunk).
    const int scode = t >> 2, sq = t & 3;
    const int swz_e = 8 * (scode & 7);

    // prologue: schunk 0 (nt=0, d0=0) into buffer 0 (eh plane only)
    {
        const float* src = emb + (size_t)scode * 256 + 16 * sq;
        float4 v4[4];
#pragma unroll
        for (int p = 0; p < 4; ++p) v4[p] = *(const float4*)(src + 4 * p);
        _Float16* dst = EB + scode * 64;
#pragma unroll
        for (int g2 = 0; g2 < 2; ++g2) {
            f16x8 oh;
#pragma unroll
            for (int i = 0; i < 8; ++i)
                oh[i] = (_Float16)(f4c(v4[(8 * g2 + i) >> 2], (8 * g2 + i) & 3)
                                   * 8192.0f);
            *(f16x8*)(dst + ((16 * sq + 8 * g2) ^ swz_e)) = oh;
        }
    }
    __syncthreads();

    // ---- preload A-fragments (X loop-invariant): 8 x f16x8 = 32 VGPR ----
    const int arow = 16 * wr + lc;
    const int aswz = 8 * (lc & 7);     // arow&7 == lc&7
    f16x8 areg[4][2];
#pragma unroll
    for (int q = 0; q < 4; ++q)
#pragma unroll
        for (int ks = 0; ks < 2; ++ks) {
            int off = (q * 64 + ks * 32 + 8 * lg) ^ aswz;
            areg[q][ks] = *(const f16x8*)&Xh[arow * 256 + off];
        }

    float sxr[4];
#pragma unroll
    for (int j = 0; j < 4; ++j)
        sxr[j] = sx2[n0 + 16 * wr + 4 * lg + j];

    float minv[4];
#pragma unroll
    for (int j = 0; j < 4; ++j) minv[j] = 3.0e38f;

    f32x4 acc[4];
#pragma unroll
    for (int ct = 0; ct < 4; ++ct) acc[ct] = (f32x4){0.f, 0.f, 0.f, 0.f};

    int brow[4], bswz[4];
#pragma unroll
    for (int ct = 0; ct < 4; ++ct) {
        int c = 64 * wc + 16 * ct + lc;
        brow[ct] = c * 64;
        bswz[ct] = 8 * (c & 7);        // == 8*(lc&7)
    }

    for (int s = 0; s < NSTEP; ++s) {
        const bool pf = (s + 1 < NSTEP);

        // T14: prefetch next schunk's fp32 E into regs
        float4 v4[4];
        if (pf) {
            const int nt1 = (s + 1) >> 2, d01 = ((s + 1) & 3) * 64;
            const float* src = emb + (size_t)(nt1 * 128 + scode) * 256
                             + d01 + 16 * sq;
#pragma unroll
            for (int p = 0; p < 4; ++p) v4[p] = *(const float4*)(src + 4 * p);
        }

        // compute: 8 MFMA / wave (2 ks x 4 ct), A from registers
        const _Float16* Ec = EB + (s & 1) * EBUF;
        const int q = s & 3;
#pragma unroll
        for (int ks = 0; ks < 2; ++ks) {
            f16x8 A = areg[q][ks];
#pragma unroll
            for (int ct = 0; ct < 4; ++ct) {
                int off = (ks * 32 + 8 * lg) ^ bswz[ct];
                f16x8 B = *(const f16x8*)&Ec[brow[ct] + off];
                acc[ct] = __builtin_amdgcn_mfma_f32_16x16x32_f16(
                    A, B, acc[ct], 0, 0, 0);
            }
        }

        // end of code-tile: prune epilogue
        if ((s & 3) == 3) {
            const int nt = s >> 2;
            const int kb = nt * 128 + 64 * wc;
#pragma unroll
            for (int j = 0; j < 4; ++j) {
                float dv[4];
                float mn = 3.0e38f;
#pragma unroll
                for (int ct = 0; ct < 4; ++ct) {
                    dv[ct] = sxr[j] - acc[ct][j] * 2.44140625e-4f;  // 2^-12
                    mn = fminf(mn, dv[ct]);
                }
#pragma unroll
                for (int msk = 1; msk <= 8; msk <<= 1)
                    mn = fminf(mn, __shfl_xor(mn, msk, 64));
                minv[j] = fminf(minv[j], mn);
                float thr = minv[j] + TAU;
                const int px = 16 * wr + 4 * lg + j;
#pragma unroll
                for (int ct = 0; ct < 4; ++ct) {
                    if (dv[ct] <= thr) {
                        int k = kb + 16 * ct + lc;
                        int qi = atomicAdd(qcnt, 1);
                        if (qi < QCAP) {
                            queue[qi] = ((unsigned)px << 13) | (unsigned)k;
                        } else {   // correct slow fallback
                            float g = exact_g(z, emb, se2, sx2, n0 + px, k);
                            unsigned long long key =
                                ((unsigned long long)__float_as_uint(g) << 32)
                                | (unsigned)k;
                            atomicMin(&pxmin[px], key);
                        }
                    }
                }
            }
#pragma unroll
            for (int ct = 0; ct < 4; ++ct) acc[ct] = (f32x4){0.f, 0.f, 0.f, 0.f};
        }

        __syncthreads();
        if (pf) {   // convert + write next schunk (eh only, swizzled)
            _Float16* dst = EB + ((s + 1) & 1) * EBUF + scode * 64;
#pragma unroll
            for (int g2 = 0; g2 < 2; ++g2) {
                f16x8 oh;
#pragma unroll
                for (int i = 0; i < 8; ++i)
                    oh[i] = (_Float16)(f4c(v4[(8 * g2 + i) >> 2],
                                           (8 * g2 + i) & 3) * 8192.0f);
                *(f16x8*)(dst + ((16 * sq + 8 * g2) ^ swz_e)) = oh;
            }
        }
        __syncthreads();
    }

    // ---- batched exact eval of all candidates (wave-parallel) ----
    int qn = *qcnt;
    if (qn > QCAP) qn = QCAP;
    for (int i = t; i < qn; i += 512) {
        unsigned e = queue[i];
        int px = e >> 13, k = e & 8191;
        float g = exact_g(z, emb, se2, sx2, n0 + px, k);
        unsigned long long key =
            ((unsigned long long)__float_as_uint(g) << 32) | (unsigned)k;
        atomicMin(&pxmin[px], key);
    }
    __syncthreads();

    if (t < 64) {
        int k = (int)(pxmin[t] & 8191u);
        out_idx[n0 + t] = (float)k;
        atomicAdd(&hist[k], 1);
    }
}

// ---------------------------------------------------------------------------
__global__ void quantize_kernel(const float* __restrict__ z,
                                const float* __restrict__ emb,
                                const float* __restrict__ idxf,
                                float* __restrict__ zq,
                                float* __restrict__ sse) {
    int o = (blockIdx.x * 256 + threadIdx.x) * 4;
    int hw = o & 1023;
    int c  = (o >> 10) & 255;
    int b  = o >> 18;
    int nbase = b * 1024 + hw;
    float4 x = *(const float4*)(z + o);
    float q0 = emb[(size_t)((int)idxf[nbase + 0]) * D_EMB + c];
    float q1 = emb[(size_t)((int)idxf[nbase + 1]) * D_EMB + c];
    float q2 = emb[(size_t)((int)idxf[nbase + 2]) * D_EMB + c];
    float q3 = emb[(size_t)((int)idxf[nbase + 3]) * D_EMB + c];
    float4 q = make_float4(q0, q1, q2, q3);
    *(float4*)(zq + o) = q;
    float d0 = q.x - x.x, d1 = q.y - x.y, d2 = q.z - x.z, d3 = q.w - x.w;
    float s = d0 * d0 + d1 * d1 + d2 * d2 + d3 * d3;
#pragma unroll
    for (int m = 1; m < 64; m <<= 1) s += __shfl_xor(s, m, 64);
    __shared__ float red[4];
    int lane = threadIdx.x & 63, wv = threadIdx.x >> 6;
    if (lane == 0) red[wv] = s;
    __syncthreads();
    if (threadIdx.x == 0)
        atomicAdd(sse, red[0] + red[1] + red[2] + red[3]);
}

// ---------------------------------------------------------------------------
__global__ void finalize_kernel(const int* __restrict__ hist,
                                const float* __restrict__ sse,
                                float* __restrict__ out) {
    float s = 0.0f;
    for (int i = threadIdx.x; i < K_EMB; i += 256) {
        float p = (float)hist[i] * (1.0f / (float)NPIX);
        s += p * logf(p + 1e-10f);
    }
#pragma unroll
    for (int m = 1; m < 64; m <<= 1) s += __shfl_xor(s, m, 64);
    __shared__ float red[4];
    int lane = threadIdx.x & 63, wv = threadIdx.x >> 6;
    if (lane == 0) red[wv] = s;
    __syncthreads();
    if (threadIdx.x == 0) {
        float H = -(red[0] + red[1] + red[2] + red[3]);
        out[OUT_PERP] = expf(H);
        out[OUT_LOSS] = 1.25f * sse[0] / (float)NDTOT;
    }
}

// ---------------------------------------------------------------------------
extern "C" void kernel_launch(void* const* d_in, const int* in_sizes, int n_in,
                              void* d_out, int out_size, void* d_ws, size_t ws_size,
                              hipStream_t stream) {
    const float* z   = (const float*)d_in[0];   // [16,256,32,32]
    const float* emb = (const float*)d_in[1];   // [8192,256]
    float* out = (float*)d_out;
    char*  ws  = (char*)d_ws;
    float* sse  = (float*)(ws);
    int*   hist = (int*)(ws + WS_HIST_OFF);
    float* se2  = (float*)(ws + WS_SE2_OFF);
    float* sx2  = (float*)(ws + WS_SX2_OFF);

    static int attr_done = 0;
    if (!attr_done) {
        (void)hipFuncSetAttribute((const void*)mfma_kernel,
                                  hipFuncAttributeMaxDynamicSharedMemorySize,
                                  SMEM_BYTES);
        attr_done = 1;
    }

    // zero sse + hist every call (graph replays don't re-poison)
    hipMemsetAsync(ws, 0, WS_SE2_OFF, stream);

    sx2_kernel<<<NPIX / 256, 256, 0, stream>>>(z, sx2);
    se2_kernel<<<K_EMB / 256, 256, 0, stream>>>(emb, se2);
    mfma_kernel<<<NPIX / TN, 512, SMEM_BYTES, stream>>>(
        z, emb, sx2, se2, out + OUT_IDX, hist);
    quantize_kernel<<<NDTOT / (256 * 4), 256, 0, stream>>>(
        z, emb, out + OUT_IDX, out + OUT_ZQ, sse);
    finalize_kernel<<<1, 256, 0, stream>>>(hist, sse, out);
}

// Round 20
// 445.998 us; speedup vs baseline: 9.0127x; 9.0127x over previous
//
#include <hip/hip_runtime.h>
#include <math.h>

// VQ-VAE quantizer: N=16384 pixels, D=256, K=8192 codes.
// d_out (float32): [0]=loss, [1..]=z_q_x, [4194305]=perplexity, [4194306..]=idx.
//
// r20 = r19 with the Rule#20 fix: r19 indexed the preloaded A-fragments as
// areg[s&3][ks] with RUNTIME s -> compiler demoted them to scratch; every
// MFMA stalled on backed-memory loads (MfmaUtil 12.4% -> 0.69%, 8.6x slower).
// Main loop is now outer nt (64) x fully-unrolled q (0..3): all areg/buffer
// indices compile-time. Otherwise identical to r19's verified structure:
// eh-only fp16 approx (eps<=5.1e-5 << TAU), XOR-swizzled conflict-free LDS,
// candidate queue + batched exact fp32-chain eval (np argmin semantics).

typedef _Float16 f16x8 __attribute__((ext_vector_type(8)));
typedef float f32x4 __attribute__((ext_vector_type(4)));

#define K_EMB 8192
#define D_EMB 256
#define NPIX  16384
#define NDTOT 4194304

#define OUT_LOSS 0
#define OUT_ZQ   1
#define OUT_PERP 4194305
#define OUT_IDX  4194306

// ws: [0]sse f32; [256]hist int[8192]; [33024]se2 f32[8192]; [65792]sx2 f32[16384]
#define WS_HIST_OFF 256
#define WS_SE2_OFF  33024
#define WS_SX2_OFF  65792

#define TAU 2.5e-4f   // >= grid 3.05e-5 + 2*eps(5.1e-5) + slack

// geometry: block = 64 px, loops 64 code-tiles of 128; 4 dchunks of 64 each.
#define TN 64
#define NT 64
#define EBUF 8192              // fp16 per buffer: 128 codes x 64 d
#define QCAP 2048

// LDS layout (bytes)
#define LDS_EB    0                       // 2 x EBUF fp16 = 32768
#define LDS_XH    32768                   // 64 x 256 fp16 = 32768
#define LDS_PXMIN 65536                   // 64 x u64 = 512
#define LDS_QCNT  66048                   // int
#define LDS_QUEUE 66064                   // QCAP x u32 = 8192
#define SMEM_BYTES 74256

// ---------------------------------------------------------------------------
__global__ void sx2_kernel(const float* __restrict__ z,
                           float* __restrict__ sx2) {
#pragma clang fp contract(off)
    int n = blockIdx.x * 256 + threadIdx.x;
    int b = n >> 10, hw = n & 1023;
    const float* zb = z + (size_t)b * (D_EMB * 1024) + hw;
    float half[2];
#pragma unroll
    for (int h = 0; h < 2; ++h) {
        float r[8];
#pragma unroll
        for (int j = 0; j < 8; ++j) {
            float v = zb[(size_t)(h * 128 + j) * 1024];
            r[j] = v * v;
        }
        for (int i = 8; i < 128; i += 8)
#pragma unroll
            for (int j = 0; j < 8; ++j) {
                float v = zb[(size_t)(h * 128 + i + j) * 1024];
                float sq = v * v;
                r[j] = r[j] + sq;
            }
        half[h] = ((r[0] + r[1]) + (r[2] + r[3]))
                + ((r[4] + r[5]) + (r[6] + r[7]));
    }
    sx2[n] = half[0] + half[1];
}

// ---------------------------------------------------------------------------
__global__ void se2_kernel(const float* __restrict__ emb,
                           float* __restrict__ se2) {
#pragma clang fp contract(off)
    int k = blockIdx.x * 256 + threadIdx.x;
    const float* e = emb + (size_t)k * D_EMB;
    float half[2];
#pragma unroll
    for (int h = 0; h < 2; ++h) {
        float r[8];
#pragma unroll
        for (int j = 0; j < 8; ++j) {
            float v = e[h * 128 + j];
            r[j] = v * v;
        }
        for (int i = 8; i < 128; i += 8)
#pragma unroll
            for (int j = 0; j < 8; ++j) {
                float v = e[h * 128 + i + j];
                float sq = v * v;
                r[j] = r[j] + sq;
            }
        half[h] = ((r[0] + r[1]) + (r[2] + r[3]))
                + ((r[4] + r[5]) + (r[6] + r[7]));
    }
    se2[k] = half[0] + half[1];
}

// ---------------------------------------------------------------------------
static __device__ __forceinline__ float f4c(float4 q, int j) {
    return (j == 0) ? q.x : (j == 1) ? q.y : (j == 2) ? q.z : q.w;
}

// exact np-semantics distance (verified r3-r19)
static __device__ __forceinline__ float exact_g(
        const float* __restrict__ z, const float* __restrict__ emb,
        const float* __restrict__ se2, const float* __restrict__ sx2,
        int n, int k) {
#pragma clang fp contract(off)
    const float* xp = z + (size_t)(n >> 10) * 262144 + (n & 1023);
    const float* ep = emb + (size_t)k * 256;
    float s = 0.0f;
    for (int d = 0; d < 256; ++d)
        s = __builtin_fmaf(xp[(size_t)d * 1024], ep[d], s);
    float A = sx2[n] + se2[k];
    return A - 2.0f * s;
}

// ---------------------------------------------------------------------------
// MFMA prune kernel. Grid 256 (one 64-px tile), 512 thr = 8 waves
// (wr 0..3: 16-px tiles, wc 0..1: 64-code halves). Loops 64 code-tiles.
// mfma_f32_16x16x32_f16; A-frag lane: A[l&15][8*(l>>4)+j]; B-frag:
// B[8*(l>>4)+j][l&15]; D: row=(l>>4)*4+j, col=l&15 (r17/r18-verified).
__global__ __launch_bounds__(512, 1) void mfma_kernel(
        const float* __restrict__ z, const float* __restrict__ emb,
        const float* __restrict__ sx2, const float* __restrict__ se2,
        float* __restrict__ out_idx, int* __restrict__ hist) {
#pragma clang fp contract(off)
    extern __shared__ char sm[];
    _Float16* EB   = (_Float16*)(sm + LDS_EB);     // [2][128][64] swizzled
    _Float16* Xh   = (_Float16*)(sm + LDS_XH);     // [64][256] swizzled
    unsigned long long* pxmin = (unsigned long long*)(sm + LDS_PXMIN);
    int*      qcnt  = (int*)(sm + LDS_QCNT);
    unsigned* queue = (unsigned*)(sm + LDS_QUEUE);

    const int t    = threadIdx.x;
    const int lane = t & 63;
    const int w    = t >> 6;
    const int wr   = w >> 1, wc = w & 1;
    const int lc   = lane & 15;
    const int lg   = lane >> 4;
    const int n0   = blockIdx.x * TN;
    const int b    = n0 >> 10, hw0 = n0 & 1023;
    const float* zb = z + (size_t)b * 262144 + hw0;

    if (t < 64) pxmin[t] = ~0ull;
    if (t == 0) *qcnt = 0;

    // ---- stage X once: [d][px] f32 -> transpose+cvt -> Xh swizzled ----
    {
        float* Xtmp = (float*)(sm + LDS_EB);       // 64d x 68px f32 slab
#pragma unroll
        for (int slab = 0; slab < 4; ++slab) {
            {
                int px = t & 63, dr = t >> 6;
#pragma unroll
                for (int r = 0; r < 8; ++r) {
                    int dl = dr * 8 + r;
                    Xtmp[dl * 68 + px] = zb[(size_t)(slab * 64 + dl) * 1024 + px];
                }
            }
            __syncthreads();
            {
                int px = t & 63, g = t >> 6;
                f16x8 v;
#pragma unroll
                for (int i = 0; i < 8; ++i)
                    v[i] = (_Float16)Xtmp[(g * 8 + i) * 68 + px];
                int off = (slab * 64 + g * 8) ^ (8 * (px & 7));
                *(f16x8*)&Xh[px * 256 + off] = v;
            }
            __syncthreads();
        }
    }

    // E staging map: thread -> code = t>>2 (0..127), sq = t&3 (16-d chunk).
    const int scode = t >> 2, sq = t & 3;
    const int swz_e = 8 * (scode & 7);

    // prologue: dchunk 0 (nt=0, d0=0) into buffer 0 (eh plane only)
    {
        const float* src = emb + (size_t)scode * 256 + 16 * sq;
        float4 v4[4];
#pragma unroll
        for (int p = 0; p < 4; ++p) v4[p] = *(const float4*)(src + 4 * p);
        _Float16* dst = EB + scode * 64;
#pragma unroll
        for (int g2 = 0; g2 < 2; ++g2) {
            f16x8 oh;
#pragma unroll
            for (int i = 0; i < 8; ++i)
                oh[i] = (_Float16)(f4c(v4[(8 * g2 + i) >> 2], (8 * g2 + i) & 3)
                                   * 8192.0f);
            *(f16x8*)(dst + ((16 * sq + 8 * g2) ^ swz_e)) = oh;
        }
    }
    __syncthreads();

    // ---- preload A-fragments (X loop-invariant): 8 x f16x8 = 32 VGPR ----
    const int arow = 16 * wr + lc;
    const int aswz = 8 * (lc & 7);     // arow&7 == lc&7
    f16x8 areg[4][2];
#pragma unroll
    for (int q = 0; q < 4; ++q)
#pragma unroll
        for (int ks = 0; ks < 2; ++ks) {
            int off = (q * 64 + ks * 32 + 8 * lg) ^ aswz;
            areg[q][ks] = *(const f16x8*)&Xh[arow * 256 + off];
        }

    float sxr[4];
#pragma unroll
    for (int j = 0; j < 4; ++j)
        sxr[j] = sx2[n0 + 16 * wr + 4 * lg + j];

    float minv[4];
#pragma unroll
    for (int j = 0; j < 4; ++j) minv[j] = 3.0e38f;

    f32x4 acc[4];
#pragma unroll
    for (int ct = 0; ct < 4; ++ct) acc[ct] = (f32x4){0.f, 0.f, 0.f, 0.f};

    int brow[4], bswz[4];
#pragma unroll
    for (int ct = 0; ct < 4; ++ct) {
        int c = 64 * wc + 16 * ct + lc;
        brow[ct] = c * 64;
        bswz[ct] = 8 * (c & 7);        // == 8*(lc&7)
    }

    // main loop: outer nt (runtime), inner q FULLY UNROLLED (compile-time
    // areg/buffer indices -- the r19 scratch-demotion fix).
    for (int nt = 0; nt < NT; ++nt) {
#pragma unroll
        for (int q = 0; q < 4; ++q) {
            const bool pf = (nt < NT - 1) || (q < 3);

            // T14: prefetch next dchunk's fp32 E into regs
            float4 v4[4];
            if (pf) {
                const int nt1 = (q == 3) ? nt + 1 : nt;
                const int d01 = ((q + 1) & 3) * 64;
                const float* src = emb + (size_t)(nt1 * 128 + scode) * 256
                                 + d01 + 16 * sq;
#pragma unroll
                for (int p = 0; p < 4; ++p)
                    v4[p] = *(const float4*)(src + 4 * p);
            }

            // compute: 8 MFMA / wave (2 ks x 4 ct), A from registers
            const _Float16* Ec = EB + (q & 1) * EBUF;
#pragma unroll
            for (int ks = 0; ks < 2; ++ks) {
                f16x8 A = areg[q][ks];             // compile-time q
#pragma unroll
                for (int ct = 0; ct < 4; ++ct) {
                    int off = (ks * 32 + 8 * lg) ^ bswz[ct];
                    f16x8 B = *(const f16x8*)&Ec[brow[ct] + off];
                    acc[ct] = __builtin_amdgcn_mfma_f32_16x16x32_f16(
                        A, B, acc[ct], 0, 0, 0);
                }
            }

            // end of code-tile: prune epilogue
            if (q == 3) {
                const int kb = nt * 128 + 64 * wc;
#pragma unroll
                for (int j = 0; j < 4; ++j) {
                    float dv[4];
                    float mn = 3.0e38f;
#pragma unroll
                    for (int ct = 0; ct < 4; ++ct) {
                        dv[ct] = sxr[j] - acc[ct][j] * 2.44140625e-4f;
                        mn = fminf(mn, dv[ct]);
                    }
#pragma unroll
                    for (int msk = 1; msk <= 8; msk <<= 1)
                        mn = fminf(mn, __shfl_xor(mn, msk, 64));
                    minv[j] = fminf(minv[j], mn);
                    float thr = minv[j] + TAU;
                    const int px = 16 * wr + 4 * lg + j;
#pragma unroll
                    for (int ct = 0; ct < 4; ++ct) {
                        if (dv[ct] <= thr) {
                            int k = kb + 16 * ct + lc;
                            int qi = atomicAdd(qcnt, 1);
                            if (qi < QCAP) {
                                queue[qi] = ((unsigned)px << 13) | (unsigned)k;
                            } else {   // correct slow fallback
                                float g = exact_g(z, emb, se2, sx2,
                                                  n0 + px, k);
                                unsigned long long key =
                                    ((unsigned long long)
                                     __float_as_uint(g) << 32) | (unsigned)k;
                                atomicMin(&pxmin[px], key);
                            }
                        }
                    }
                }
#pragma unroll
                for (int ct = 0; ct < 4; ++ct)
                    acc[ct] = (f32x4){0.f, 0.f, 0.f, 0.f};
            }

            __syncthreads();
            if (pf) {   // convert + write next dchunk (eh only, swizzled)
                _Float16* dst = EB + ((q + 1) & 1) * EBUF + scode * 64;
#pragma unroll
                for (int g2 = 0; g2 < 2; ++g2) {
                    f16x8 oh;
#pragma unroll
                    for (int i = 0; i < 8; ++i)
                        oh[i] = (_Float16)(f4c(v4[(8 * g2 + i) >> 2],
                                               (8 * g2 + i) & 3) * 8192.0f);
                    *(f16x8*)(dst + ((16 * sq + 8 * g2) ^ swz_e)) = oh;
                }
            }
            __syncthreads();
        }
    }

    // ---- batched exact eval of all candidates (wave-parallel) ----
    int qn = *qcnt;
    if (qn > QCAP) qn = QCAP;
    for (int i = t; i < qn; i += 512) {
        unsigned e = queue[i];
        int px = e >> 13, k = e & 8191;
        float g = exact_g(z, emb, se2, sx2, n0 + px, k);
        unsigned long long key =
            ((unsigned long long)__float_as_uint(g) << 32) | (unsigned)k;
        atomicMin(&pxmin[px], key);
    }
    __syncthreads();

    if (t < 64) {
        int k = (int)(pxmin[t] & 8191u);
        out_idx[n0 + t] = (float)k;
        atomicAdd(&hist[k], 1);
    }
}

// ---------------------------------------------------------------------------
__global__ void quantize_kernel(const float* __restrict__ z,
                                const float* __restrict__ emb,
                                const float* __restrict__ idxf,
                                float* __restrict__ zq,
                                float* __restrict__ sse) {
    int o = (blockIdx.x * 256 + threadIdx.x) * 4;
    int hw = o & 1023;
    int c  = (o >> 10) & 255;
    int b  = o >> 18;
    int nbase = b * 1024 + hw;
    float4 x = *(const float4*)(z + o);
    float q0 = emb[(size_t)((int)idxf[nbase + 0]) * D_EMB + c];
    float q1 = emb[(size_t)((int)idxf[nbase + 1]) * D_EMB + c];
    float q2 = emb[(size_t)((int)idxf[nbase + 2]) * D_EMB + c];
    float q3 = emb[(size_t)((int)idxf[nbase + 3]) * D_EMB + c];
    float4 q = make_float4(q0, q1, q2, q3);
    *(float4*)(zq + o) = q;
    float d0 = q.x - x.x, d1 = q.y - x.y, d2 = q.z - x.z, d3 = q.w - x.w;
    float s = d0 * d0 + d1 * d1 + d2 * d2 + d3 * d3;
#pragma unroll
    for (int m = 1; m < 64; m <<= 1) s += __shfl_xor(s, m, 64);
    __shared__ float red[4];
    int lane = threadIdx.x & 63, wv = threadIdx.x >> 6;
    if (lane == 0) red[wv] = s;
    __syncthreads();
    if (threadIdx.x == 0)
        atomicAdd(sse, red[0] + red[1] + red[2] + red[3]);
}

// ---------------------------------------------------------------------------
__global__ void finalize_kernel(const int* __restrict__ hist,
                                const float* __restrict__ sse,
                                float* __restrict__ out) {
    float s = 0.0f;
    for (int i = threadIdx.x; i < K_EMB; i += 256) {
        float p = (float)hist[i] * (1.0f / (float)NPIX);
        s += p * logf(p + 1e-10f);
    }
#pragma unroll
    for (int m = 1; m < 64; m <<= 1) s += __shfl_xor(s, m, 64);
    __shared__ float red[4];
    int lane = threadIdx.x & 63, wv = threadIdx.x >> 6;
    if (lane == 0) red[wv] = s;
    __syncthreads();
    if (threadIdx.x == 0) {
        float H = -(red[0] + red[1] + red[2] + red[3]);
        out[OUT_PERP] = expf(H);
        out[OUT_LOSS] = 1.25f * sse[0] / (float)NDTOT;
    }
}

// ---------------------------------------------------------------------------
extern "C" void kernel_launch(void* const* d_in, const int* in_sizes, int n_in,
                              void* d_out, int out_size, void* d_ws, size_t ws_size,
                              hipStream_t stream) {
    const float* z   = (const float*)d_in[0];   // [16,256,32,32]
    const float* emb = (const float*)d_in[1];   // [8192,256]
    float* out = (float*)d_out;
    char*  ws  = (char*)d_ws;
    float* sse  = (float*)(ws);
    int*   hist = (int*)(ws + WS_HIST_OFF);
    float* se2  = (float*)(ws + WS_SE2_OFF);
    float* sx2  = (float*)(ws + WS_SX2_OFF);

    static int attr_done = 0;
    if (!attr_done) {
        (void)hipFuncSetAttribute((const void*)mfma_kernel,
                                  hipFuncAttributeMaxDynamicSharedMemorySize,
                                  SMEM_BYTES);
        attr_done = 1;
    }

    // zero sse + hist every call (graph replays don't re-poison)
    hipMemsetAsync(ws, 0, WS_SE2_OFF, stream);

    sx2_kernel<<<NPIX / 256, 256, 0, stream>>>(z, sx2);
    se2_kernel<<<K_EMB / 256, 256, 0, stream>>>(emb, se2);
    mfma_kernel<<<NPIX / TN, 512, SMEM_BYTES, stream>>>(
        z, emb, sx2, se2, out + OUT_IDX, hist);
    quantize_kernel<<<NDTOT / (256 * 4), 256, 0, stream>>>(
        z, emb, out + OUT_IDX, out + OUT_ZQ, sse);
    finalize_kernel<<<1, 256, 0, stream>>>(hist, sse, out);
}